// Round 5
// baseline (231259.570 us; speedup 1.0000x reference)
//
#include <hip/hip_runtime.h>
#include <stdint.h>

typedef float f32x4 __attribute__((ext_vector_type(4)));

#define SLEN 8192
#define NBLK 256

// rings: h1 at byte 0, h0 at 16384. Each: 2 parities x 256 CUs x 2 chunks x 16B.
// CU j, chunk0 = {h[4j],h[4j+1],h[4j+2],tag}, chunk1 = {h[4j+3], ypsum_j, 0, tag}
#define RING_PAR 8192
#define H0_OFF   16384
#define WS_BYTES 32768

__device__ __forceinline__ void st_chunk(void* addr, f32x4 v) {
  asm volatile("global_store_dwordx4 %0, %1, off sc0 sc1"
               :: "v"(addr), "v"(v) : "memory");
}
// coherent (IC-direct) load pair — fallback path, known-good
__device__ __forceinline__ void ld2_coh(const void* a, f32x4& v0, f32x4& v1) {
  asm volatile("global_load_dwordx4 %0, %2, off sc0 sc1\n\t"
               "global_load_dwordx4 %1, %2, off offset:16 sc0 sc1\n\t"
               "s_waitcnt vmcnt(0)"
               : "=v"(v0), "=v"(v1) : "v"(a) : "memory");
}
// cached load pair — coalescable, L2-shareable across the XCD
__device__ __forceinline__ void ld2_cached(const void* a, f32x4& v0, f32x4& v1) {
  asm volatile("global_load_dwordx4 %0, %2, off\n\t"
               "global_load_dwordx4 %1, %2, off offset:16\n\t"
               "s_waitcnt vmcnt(0)"
               : "=v"(v0), "=v"(v1) : "v"(a) : "memory");
}
// poll a 32B (2-chunk) slot until both embedded tags equal 'tag'.
// Strategy: acquire-fence (buffer_inv: invalidate stale L1/L2 lines) + cached
// load; publishers wrote through to IC, so the refill is fresh and the line is
// SHARED via the per-XCD L2 (32 CUs -> 128 IC line-fills instead of 16k
// serialized coherent-bypass loads). Fallback to sc0sc1 after 16 tries.
__device__ __forceinline__ void poll2(const void* a, unsigned tag, f32x4& v0, f32x4& v1) {
  __builtin_amdgcn_fence(__ATOMIC_ACQUIRE, "agent");
  ld2_cached(a, v0, v1);
  int tries = 0;
  while (__float_as_uint(v0.w) != tag || __float_as_uint(v1.w) != tag) {
    if (++tries < 16) {
      __builtin_amdgcn_fence(__ATOMIC_ACQUIRE, "agent");
      ld2_cached(a, v0, v1);
    } else {
      __builtin_amdgcn_s_sleep(1);
      ld2_coh(a, v0, v1);
    }
  }
}

__device__ __forceinline__ float sigm(float v) { return 1.f / (1.f + expf(-v)); }
__device__ __forceinline__ float tanh_f(float v) {
  float e = expf(-2.f * fabsf(v));
  return copysignf((1.f - e) / (1.f + e), v);
}
__device__ __forceinline__ float lstm_h(float a0, float a1, float a2, float a3, float& c) {
  float ii = sigm(a0), ff = sigm(a1), gg = tanh_f(a2), oo = sigm(a3);
  c = ff * c + ii * gg;
  return oo * tanh_f(c);
}

// wave64 sum via DPP (row_shr 1,2,4,8 then bcast15/31); total lands in lane 63
__device__ __forceinline__ float dpp_red(float x) {
  x += __int_as_float(__builtin_amdgcn_update_dpp(0, __float_as_int(x), 0x111, 0xf, 0xf, true));
  x += __int_as_float(__builtin_amdgcn_update_dpp(0, __float_as_int(x), 0x112, 0xf, 0xf, true));
  x += __int_as_float(__builtin_amdgcn_update_dpp(0, __float_as_int(x), 0x114, 0xf, 0xf, true));
  x += __int_as_float(__builtin_amdgcn_update_dpp(0, __float_as_int(x), 0x118, 0xf, 0xf, true));
  x += __int_as_float(__builtin_amdgcn_update_dpp(0, __float_as_int(x), 0x142, 0xa, 0xf, true));
  x += __int_as_float(__builtin_amdgcn_update_dpp(0, __float_as_int(x), 0x143, 0xc, 0xf, true));
  return x;
}

__device__ __forceinline__ float dot4(f32x4 a, f32x4 b) {
  return a.x * b.x + a.y * b.y + a.z * b.z + a.w * b.w;
}
// padded hidden-vector layout: chunk stride 20 floats (80B) -> conflict-free b128
__device__ __forceinline__ int lds_idx4(int j) { return (j >> 2) * 20 + (j & 3) * 4; }

__global__ __launch_bounds__(512, 2) void lstm_fused(
    const float* __restrict__ x, const int* __restrict__ mask,
    const float* __restrict__ feat, const int* __restrict__ tfp,
    const float* __restrict__ w_ih0, const float* __restrict__ w_hh0,
    const float* __restrict__ b_ih0, const float* __restrict__ b_hh0,
    const float* __restrict__ w_ih1, const float* __restrict__ w_hh1,
    const float* __restrict__ b_ih1, const float* __restrict__ b_hh1,
    const float* __restrict__ w_ffn, const float* __restrict__ b_ffn,
    float* __restrict__ out, char* __restrict__ ws)
{
  char* h1ring = ws;
  char* h0ring = ws + H0_OFF;
  const int tid = threadIdx.x, lane = tid & 63, wv = tid >> 6;
  const int blk = blockIdx.x;
  const int u = wv & 3;                 // unit within CU
  const int m = blk * 4 + u;            // owned global hidden unit
  const bool L1w = wv < 4;              // waves 0-3: layer-1 ; waves 4-7: layer-0

  __shared__ __align__(16) float wh1_lds[16 * 1280];   // 80 KB, pad-20 chunks
  __shared__ __align__(16) float lh0[1280];            // h0[t-1] -> h0[t]
  __shared__ __align__(16) float lh1[2][1280];         // h1 double-buffer by parity
  __shared__ float lyp[256];
  __shared__ float g1h[4], g1yp[4], g0h[4];
  __shared__ float lys;

  // ---- per-role weight matrix (union: 64 VGPRs total) ----
  f32x4 W[4][4];
  {
    const float* Wsrc = L1w ? w_ih1 : w_hh0;
#pragma unroll
    for (int g = 0; g < 4; ++g) {
      const f32x4* s = reinterpret_cast<const f32x4*>(
          Wsrc + (size_t)(1024 * g + m) * 1024 + lane * 16);
#pragma unroll
      for (int q = 0; q < 4; ++q) W[g][q] = s[q];
    }
  }
  float wA[4], wB[4];
#pragma unroll
  for (int g = 0; g < 4; ++g) {
    const int r = 1024 * g + m;
    if (L1w) {
      wA[g] = (lane == 16) ? (b_ih1[r] + b_hh1[r]) : 0.f;   // layer-1 bias slot
      wB[g] = 0.f;
    } else {
      wA[g] = (lane < 16) ? w_ih0[r * 16 + lane]
            : (lane == 16 ? (b_ih0[r] + b_hh0[r]) : 0.f);
      wB[g] = w_ih0[r * 16];                                 // scalar-input column
    }
  }
  const float wffn = w_ffn[m];
  const float bf = b_ffn[0];
  float cc = 0.f;                       // c1 on L1 lane63, c0 on L0 lane63
  float ap[4] = {0.f, 0.f, 0.f, 0.f};   // L1: bb + wh1*h1[t-2] prefetch

  // ---- stage w_hh1 into LDS (pad-20 layout) ----
  for (int ch = tid; ch < 1024; ch += 512) {
    const int r = ch >> 6, kc = ch & 63;
    const int grow = 1024 * (r & 3) + blk * 4 + (r >> 2);
    const f32x4* src = reinterpret_cast<const f32x4*>(
        w_hh1 + (size_t)grow * 1024 + kc * 16);
    f32x4* dst = reinterpret_cast<f32x4*>(&wh1_lds[r * 1280 + kc * 20]);
    dst[0] = src[0]; dst[1] = src[1]; dst[2] = src[2]; dst[3] = src[3];
  }
  __syncthreads();

  const bool tf1 = (*tfp) >= 1;

  for (int t = 0; t < SLEN; ++t) {
    const bool use_x = (t == 0) || (tf1 && mask[t] != 0);
    const bool needy = (t > 0) && !use_x;
    float acc0[4];

    // issue L0 per-step input loads early (overlap S1 region)
    float base = 0.f;
    if (!L1w) {
      base = (lane == 0) ? (use_x ? x[t] : 0.f)
           : (lane < 16) ? feat[t * 15 + lane - 1]
           : (lane == 16) ? 1.f : 0.f;
    }

    // ---- step1: L1 computes h1[t-1] = gates(ap + wi1*h0[t-1]) ----
    if (L1w && t > 0) {
      const f32x4* hv = reinterpret_cast<const f32x4*>(&lh0[lane * 20]);
      f32x4 h0v = hv[0], h1v = hv[1], h2v = hv[2], h3v = hv[3];
      float a[4];
#pragma unroll
      for (int g = 0; g < 4; ++g)
        a[g] = ap[g] + dot4(W[g][0], h0v) + dot4(W[g][1], h1v) +
                        dot4(W[g][2], h2v) + dot4(W[g][3], h3v);
#pragma unroll
      for (int g = 0; g < 4; ++g) a[g] = dpp_red(a[g]);
      if (lane == 63) {
        float h = lstm_h(a[0], a[1], a[2], a[3], cc);
        g1h[u] = h; g1yp[u] = wffn * h;
      }
    }
    __syncthreads();  // S1

    // ---- step2: pub h1[t-1] ; L0 matvec ; L1 polls h1[t-1] ----
    if (t > 0 && tid < 2) {
      f32x4 v;
      if (tid == 0) { v.x = g1h[0]; v.y = g1h[1]; v.z = g1h[2]; }
      else { v.x = g1h[3]; v.y = (g1yp[0] + g1yp[1]) + (g1yp[2] + g1yp[3]); v.z = 0.f; }
      v.w = __uint_as_float((unsigned)(t - 1));
      st_chunk(h1ring + ((t - 1) & 1) * RING_PAR + blk * 32 + tid * 16, v);
    }
    if (!L1w) {
#pragma unroll
      for (int g = 0; g < 4; ++g) acc0[g] = wA[g] * base;
      if (t > 0) {
        const f32x4* hv = reinterpret_cast<const f32x4*>(&lh0[lane * 20]);
        f32x4 h0v = hv[0], h1v = hv[1], h2v = hv[2], h3v = hv[3];
#pragma unroll
        for (int g = 0; g < 4; ++g)
          acc0[g] += dot4(W[g][0], h0v) + dot4(W[g][1], h1v) +
                     dot4(W[g][2], h2v) + dot4(W[g][3], h3v);
      }
#pragma unroll
      for (int g = 0; g < 4; ++g) acc0[g] = dpp_red(acc0[g]);
    } else if (t > 0) {
      f32x4 v0, v1;  // tid < 256 here
      poll2(h1ring + ((t - 1) & 1) * RING_PAR + tid * 32, (unsigned)(t - 1), v0, v1);
      f32x4 hv; hv.x = v0.x; hv.y = v0.y; hv.z = v0.z; hv.w = v1.x;
      *reinterpret_cast<f32x4*>(&lh1[(t - 1) & 1][lds_idx4(tid)]) = hv;
      lyp[tid] = v1.y;
    }
    __syncthreads();  // S2

    // ---- step3: y[t-1] reduce (wave0), out write ----
    if (t > 0 && wv == 0) {
      float s = (lyp[lane * 4] + lyp[lane * 4 + 1]) + (lyp[lane * 4 + 2] + lyp[lane * 4 + 3]);
      s = dpp_red(s);
      if (lane == 63) {
        float yy = s + bf;
        lys = yy;
        if (blk == 0) out[t - 1] = yy;
      }
    }
    __syncthreads();  // S3

    // ---- step4: L0 finishes h0[t] gates ----
    if (!L1w && lane == 63) {
      if (needy) {
        float yy = lys;
#pragma unroll
        for (int g = 0; g < 4; ++g) acc0[g] += yy * wB[g];
      }
      float h = lstm_h(acc0[0], acc0[1], acc0[2], acc0[3], cc);
      g0h[u] = h;
    }
    __syncthreads();  // S4

    // ---- step5: pub h0[t] ; L1 prefetch ap=bb+wh1*h1[t-1] ; L0 polls h0[t] ----
    if (tid < 2) {
      f32x4 v;
      if (tid == 0) { v.x = g0h[0]; v.y = g0h[1]; v.z = g0h[2]; }
      else { v.x = g0h[3]; v.y = 0.f; v.z = 0.f; }
      v.w = __uint_as_float((unsigned)t);
      st_chunk(h0ring + (t & 1) * RING_PAR + blk * 32 + tid * 16, v);
    }
    if (L1w) {
#pragma unroll
      for (int g = 0; g < 4; ++g) ap[g] = wA[g];
      if (t > 0) {
        const f32x4* hv = reinterpret_cast<const f32x4*>(&lh1[(t - 1) & 1][lane * 20]);
        f32x4 h0v = hv[0], h1v = hv[1], h2v = hv[2], h3v = hv[3];
#pragma unroll
        for (int g = 0; g < 4; ++g) {
          const f32x4* wb = reinterpret_cast<const f32x4*>(
              &wh1_lds[(u * 4 + g) * 1280 + lane * 20]);
          ap[g] += dot4(wb[0], h0v) + dot4(wb[1], h1v) +
                   dot4(wb[2], h2v) + dot4(wb[3], h3v);
        }
      }
    } else {
      const int j = tid - 256;
      f32x4 v0, v1;
      poll2(h0ring + (t & 1) * RING_PAR + j * 32, (unsigned)t, v0, v1);
      f32x4 hv; hv.x = v0.x; hv.y = v0.y; hv.z = v0.z; hv.w = v1.x;
      *reinterpret_cast<f32x4*>(&lh0[lds_idx4(j)]) = hv;
    }
    __syncthreads();  // S5
  }

  // ---- tail: h1[SLEN-1] and out[SLEN-1] ----
  if (L1w) {
    const f32x4* hv = reinterpret_cast<const f32x4*>(&lh0[lane * 20]);
    f32x4 h0v = hv[0], h1v = hv[1], h2v = hv[2], h3v = hv[3];
    float a[4];
#pragma unroll
    for (int g = 0; g < 4; ++g)
      a[g] = ap[g] + dot4(W[g][0], h0v) + dot4(W[g][1], h1v) +
                      dot4(W[g][2], h2v) + dot4(W[g][3], h3v);
#pragma unroll
    for (int g = 0; g < 4; ++g) a[g] = dpp_red(a[g]);
    if (lane == 63) {
      float h = lstm_h(a[0], a[1], a[2], a[3], cc);
      g1h[u] = h; g1yp[u] = wffn * h;
    }
  }
  __syncthreads();
  if (tid < 2) {
    f32x4 v;
    if (tid == 0) { v.x = g1h[0]; v.y = g1h[1]; v.z = g1h[2]; }
    else { v.x = g1h[3]; v.y = (g1yp[0] + g1yp[1]) + (g1yp[2] + g1yp[3]); v.z = 0.f; }
    v.w = __uint_as_float((unsigned)(SLEN - 1));
    st_chunk(h1ring + ((SLEN - 1) & 1) * RING_PAR + blk * 32 + tid * 16, v);
  }
  if (blk == 0) {
    if (tid < 256) {
      f32x4 v0, v1;
      poll2(h1ring + ((SLEN - 1) & 1) * RING_PAR + tid * 32, (unsigned)(SLEN - 1), v0, v1);
      lyp[tid] = v1.y;
    }
    __syncthreads();
    if (wv == 0) {
      float s = (lyp[lane * 4] + lyp[lane * 4 + 1]) + (lyp[lane * 4 + 2] + lyp[lane * 4 + 3]);
      s = dpp_red(s);
      if (lane == 63) out[SLEN - 1] = s + bf;
    }
  }
}

extern "C" void kernel_launch(void* const* d_in, const int* in_sizes, int n_in,
                              void* d_out, int out_size, void* d_ws, size_t ws_size,
                              hipStream_t stream) {
  (void)in_sizes; (void)n_in; (void)out_size; (void)ws_size;
  const float* x      = (const float*)d_in[0];
  const int*   mask   = (const int*)  d_in[1];
  const float* feat   = (const float*)d_in[2];
  const int*   tfp    = (const int*)  d_in[3];
  const float* w_ih0  = (const float*)d_in[4];
  const float* w_hh0  = (const float*)d_in[5];
  const float* b_ih0  = (const float*)d_in[6];
  const float* b_hh0  = (const float*)d_in[7];
  const float* w_ih1  = (const float*)d_in[8];
  const float* w_hh1  = (const float*)d_in[9];
  const float* b_ih1  = (const float*)d_in[10];
  const float* b_hh1  = (const float*)d_in[11];
  const float* w_ffn  = (const float*)d_in[12];
  const float* b_ffn  = (const float*)d_in[13];
  float* out = (float*)d_out;
  char*  ws  = (char*)d_ws;

  // invalidate chunk tags (0xFFFFFFFF never equals a step index)
  hipMemsetAsync(d_ws, 0xFF, (size_t)WS_BYTES, stream);

  lstm_fused<<<dim3(NBLK), dim3(512), 0, stream>>>(
      x, mask, feat, tfp, w_ih0, w_hh0, b_ih0, b_hh0,
      w_ih1, w_hh1, b_ih1, b_hh1, w_ffn, b_ffn, out, ws);
}

// Round 6
// 41069.852 us; speedup vs baseline: 5.6309x; 5.6309x over previous
//
#include <hip/hip_runtime.h>
#include <stdint.h>

typedef float f32x4 __attribute__((ext_vector_type(4)));

#define SLEN 8192
#define NBLK 256

// rings: h1 at byte 0, h0 at 16384. Each: 2 parities x 256 CUs x 2 chunks x 16B.
// CU j, chunk0 = {h[4j],h[4j+1],h[4j+2],tag}, chunk1 = {h[4j+3], ypsum_j, 0, tag}
// All ring traffic uses sc0 sc1 (proven coherent cross-XCD; no cache-stale hazards).
#define RING_PAR 8192
#define H0_OFF   16384
#define WS_BYTES 32768

__device__ __forceinline__ void st_chunk(void* addr, f32x4 v) {
  asm volatile("global_store_dwordx4 %0, %1, off sc0 sc1"
               :: "v"(addr), "v"(v) : "memory");
}
__device__ __forceinline__ f32x4 ld_chunk(const void* a) {
  f32x4 v;
  asm volatile("global_load_dwordx4 %0, %1, off sc0 sc1\n\ts_waitcnt vmcnt(0)"
               : "=v"(v) : "v"(a) : "memory");
  return v;
}
__device__ __forceinline__ void ld2(const void* a, f32x4& v0, f32x4& v1) {
  asm volatile("global_load_dwordx4 %0, %2, off sc0 sc1\n\t"
               "global_load_dwordx4 %1, %2, off offset:16 sc0 sc1\n\t"
               "s_waitcnt vmcnt(0)"
               : "=v"(v0), "=v"(v1) : "v"(a) : "memory");
}
__device__ __forceinline__ void poll2(const void* a, unsigned tag, f32x4& v0, f32x4& v1) {
  ld2(a, v0, v1);
  while (__float_as_uint(v0.w) != tag || __float_as_uint(v1.w) != tag) {
    __builtin_amdgcn_s_sleep(1);
    ld2(a, v0, v1);
  }
}
__device__ __forceinline__ f32x4 poll1(const void* a, unsigned tag) {
  f32x4 v = ld_chunk(a);
  while (__float_as_uint(v.w) != tag) {
    __builtin_amdgcn_s_sleep(1);
    v = ld_chunk(a);
  }
  return v;
}

__device__ __forceinline__ float sigm(float v) { return 1.f / (1.f + expf(-v)); }
__device__ __forceinline__ float tanh_f(float v) {
  float e = expf(-2.f * fabsf(v));
  return copysignf((1.f - e) / (1.f + e), v);
}
__device__ __forceinline__ float lstm_h(float a0, float a1, float a2, float a3, float& c) {
  float ii = sigm(a0), ff = sigm(a1), gg = tanh_f(a2), oo = sigm(a3);
  c = ff * c + ii * gg;
  return oo * tanh_f(c);
}

// wave64 sum via DPP (row_shr 1,2,4,8 then bcast15/31); total lands in lane 63
__device__ __forceinline__ float dpp_red(float x) {
  x += __int_as_float(__builtin_amdgcn_update_dpp(0, __float_as_int(x), 0x111, 0xf, 0xf, true));
  x += __int_as_float(__builtin_amdgcn_update_dpp(0, __float_as_int(x), 0x112, 0xf, 0xf, true));
  x += __int_as_float(__builtin_amdgcn_update_dpp(0, __float_as_int(x), 0x114, 0xf, 0xf, true));
  x += __int_as_float(__builtin_amdgcn_update_dpp(0, __float_as_int(x), 0x118, 0xf, 0xf, true));
  x += __int_as_float(__builtin_amdgcn_update_dpp(0, __float_as_int(x), 0x142, 0xa, 0xf, true));
  x += __int_as_float(__builtin_amdgcn_update_dpp(0, __float_as_int(x), 0x143, 0xc, 0xf, true));
  return x;
}
__device__ __forceinline__ float dot4(f32x4 a, f32x4 b) {
  return a.x * b.x + a.y * b.y + a.z * b.z + a.w * b.w;
}
// padded hidden-vector layout: chunk stride 20 floats (80B) -> conflict-free b128
__device__ __forceinline__ int lds_idx4(int j) { return (j >> 2) * 20 + (j & 3) * 4; }

__global__ __launch_bounds__(512, 2) void lstm_fused(
    const float* __restrict__ x, const int* __restrict__ mask,
    const float* __restrict__ feat, const int* __restrict__ tfp,
    const float* __restrict__ w_ih0, const float* __restrict__ w_hh0,
    const float* __restrict__ b_ih0, const float* __restrict__ b_hh0,
    const float* __restrict__ w_ih1, const float* __restrict__ w_hh1,
    const float* __restrict__ b_ih1, const float* __restrict__ b_hh1,
    const float* __restrict__ w_ffn, const float* __restrict__ b_ffn,
    float* __restrict__ out, char* __restrict__ ws)
{
  char* h1ring = ws;
  char* h0ring = ws + H0_OFF;
  const int tid = threadIdx.x, lane = tid & 63, wv = tid >> 6;
  const int blk = blockIdx.x;
  const int u = wv & 3;
  const int m = blk * 4 + u;            // owned hidden unit (both layers)
  const bool L1w = wv < 4;              // waves 0-3: layer-1 ; waves 4-7: layer-0

  __shared__ __align__(16) float wh1_lds[16 * 1280];   // 80 KB
  __shared__ __align__(16) float lh0[1280];            // h0[t-1]
  __shared__ __align__(16) float lh1[1280];            // h1[t-2]
  __shared__ float lyp[256];
  __shared__ float g1h[4], g1yp[4], g0h[4];
  __shared__ float lys;

  // ---- per-role weight matrix in VGPRs ----
  f32x4 W[4][4];
  {
    const float* Wsrc = L1w ? w_ih1 : w_hh0;
#pragma unroll
    for (int g = 0; g < 4; ++g) {
      const f32x4* s = reinterpret_cast<const f32x4*>(
          Wsrc + (size_t)(1024 * g + m) * 1024 + lane * 16);
#pragma unroll
      for (int q = 0; q < 4; ++q) W[g][q] = s[q];
    }
  }
  float wA[4], wB[4];
#pragma unroll
  for (int g = 0; g < 4; ++g) {
    const int r = 1024 * g + m;
    if (L1w) {
      wA[g] = (lane == 16) ? (b_ih1[r] + b_hh1[r]) : 0.f;
      wB[g] = 0.f;
    } else {
      wA[g] = (lane < 16) ? w_ih0[r * 16 + lane]
            : (lane == 16 ? (b_ih0[r] + b_hh0[r]) : 0.f);
      wB[g] = w_ih0[r * 16];
    }
  }
  const float wffn = w_ffn[m];
  const float bf = b_ffn[0];
  float cc = 0.f;

  // ---- stage w_hh1 into LDS (pad-20 layout) ----
  for (int ch = tid; ch < 1024; ch += 512) {
    const int r = ch >> 6, kc = ch & 63;
    const int grow = 1024 * (r & 3) + blk * 4 + (r >> 2);
    const f32x4* src = reinterpret_cast<const f32x4*>(
        w_hh1 + (size_t)grow * 1024 + kc * 16);
    f32x4* dst = reinterpret_cast<f32x4*>(&wh1_lds[r * 1280 + kc * 20]);
    dst[0] = src[0]; dst[1] = src[1]; dst[2] = src[2]; dst[3] = src[3];
  }
  __syncthreads();

  const bool tf1 = (*tfp) >= 1;

  for (int t = 0; t < SLEN; ++t) {
    const bool use_x = (t == 0) || (tf1 && mask[t] != 0);
    const bool needy = (t > 0) && !use_x;
    float acc0[4];

    // ================= P1: L1 full gate matvec ; L0 matvec ; deferred y =========
    if (L1w) {
      if (t > 0) {
        __builtin_amdgcn_s_setprio(1);
        float a[4];
        const f32x4* h0v = reinterpret_cast<const f32x4*>(&lh0[lane * 20]);
        f32x4 p0 = h0v[0], p1 = h0v[1], p2 = h0v[2], p3 = h0v[3];
#pragma unroll
        for (int g = 0; g < 4; ++g)
          a[g] = wA[g] + dot4(W[g][0], p0) + dot4(W[g][1], p1) +
                          dot4(W[g][2], p2) + dot4(W[g][3], p3);
        if (t > 1) {
          const f32x4* h1v = reinterpret_cast<const f32x4*>(&lh1[lane * 20]);
          f32x4 q0 = h1v[0], q1 = h1v[1], q2 = h1v[2], q3 = h1v[3];
#pragma unroll
          for (int g = 0; g < 4; ++g) {
            const f32x4* wb = reinterpret_cast<const f32x4*>(
                &wh1_lds[(u * 4 + g) * 1280 + lane * 20]);
            a[g] += dot4(wb[0], q0) + dot4(wb[1], q1) +
                    dot4(wb[2], q2) + dot4(wb[3], q3);
          }
        }
#pragma unroll
        for (int g = 0; g < 4; ++g) a[g] = dpp_red(a[g]);
        if (lane == 63) {
          float h = lstm_h(a[0], a[1], a[2], a[3], cc);
          g1h[u] = h; g1yp[u] = wffn * h;
        }
        __builtin_amdgcn_s_setprio(0);
      }
    } else {
      float base = (lane == 0) ? (use_x ? x[t] : 0.f)
                 : (lane < 16) ? feat[t * 15 + lane - 1]
                 : (lane == 16) ? 1.f : 0.f;
#pragma unroll
      for (int g = 0; g < 4; ++g) acc0[g] = wA[g] * base;
      if (t > 0) {
        const f32x4* h0v = reinterpret_cast<const f32x4*>(&lh0[lane * 20]);
        f32x4 p0 = h0v[0], p1 = h0v[1], p2 = h0v[2], p3 = h0v[3];
#pragma unroll
        for (int g = 0; g < 4; ++g)
          acc0[g] += dot4(W[g][0], p0) + dot4(W[g][1], p1) +
                     dot4(W[g][2], p2) + dot4(W[g][3], p3);
      }
#pragma unroll
      for (int g = 0; g < 4; ++g) acc0[g] = dpp_red(acc0[g]);
      // deferred out[t-2] (only when step t-1 used x, so y wasn't reduced then)
      if (blk == 0 && wv == 4 && t >= 2 && (tf1 && mask[t - 1] != 0)) {
        float s = (lyp[lane * 4] + lyp[lane * 4 + 1]) +
                  (lyp[lane * 4 + 2] + lyp[lane * 4 + 3]);
        s = dpp_red(s);
        if (lane == 63) out[t - 2] = s + bf;
      }
    }
    __syncthreads();  // A

    // ================= P2: publish h1[t-1] ; (needy) slim y rendezvous ; gates ===
    if (t > 0 && tid < 2) {
      f32x4 v;
      if (tid == 0) { v.x = g1h[0]; v.y = g1h[1]; v.z = g1h[2]; }
      else { v.x = g1h[3]; v.y = (g1yp[0] + g1yp[1]) + (g1yp[2] + g1yp[3]); v.z = 0.f; }
      v.w = __uint_as_float((unsigned)(t - 1));
      st_chunk(h1ring + ((t - 1) & 1) * RING_PAR + blk * 32 + tid * 16, v);
    }
    if (needy) {
      if (tid < 256) {   // poll ONLY the ypart chunk (16B per thread)
        f32x4 v = poll1(h1ring + ((t - 1) & 1) * RING_PAR + tid * 32 + 16,
                        (unsigned)(t - 1));
        lyp[tid] = v.y;
      }
      __syncthreads();  // B
      if (wv == 0) {
        float s = (lyp[lane * 4] + lyp[lane * 4 + 1]) +
                  (lyp[lane * 4 + 2] + lyp[lane * 4 + 3]);
        s = dpp_red(s);
        if (lane == 63) {
          float yy = s + bf;
          lys = yy;
          if (blk == 0) out[t - 1] = yy;
        }
      }
      __syncthreads();  // C
    }
    if (!L1w && lane == 63) {
      __builtin_amdgcn_s_setprio(1);
      if (needy) {
        float yy = lys;
#pragma unroll
        for (int g = 0; g < 4; ++g) acc0[g] += yy * wB[g];
      }
      float h = lstm_h(acc0[0], acc0[1], acc0[2], acc0[3], cc);
      g0h[u] = h;
      __builtin_amdgcn_s_setprio(0);
    }
    __syncthreads();  // D

    // ================= P3: publish h0[t] ; concurrent polls (h0 by L0, h1 by L1) =
    if (tid < 2) {
      f32x4 v;
      if (tid == 0) { v.x = g0h[0]; v.y = g0h[1]; v.z = g0h[2]; }
      else { v.x = g0h[3]; v.y = 0.f; v.z = 0.f; }
      v.w = __uint_as_float((unsigned)t);
      st_chunk(h0ring + (t & 1) * RING_PAR + blk * 32 + tid * 16, v);
    }
    if (L1w) {
      if (t > 0) {   // stage h1[t-1] -> lh1 (+ yparts for possible deferral)
        f32x4 v0, v1;
        poll2(h1ring + ((t - 1) & 1) * RING_PAR + tid * 32, (unsigned)(t - 1), v0, v1);
        f32x4 hv; hv.x = v0.x; hv.y = v0.y; hv.z = v0.z; hv.w = v1.x;
        *reinterpret_cast<f32x4*>(&lh1[lds_idx4(tid)]) = hv;
        lyp[tid] = v1.y;
      }
    } else {
      const int j = tid - 256;
      f32x4 v0, v1;
      poll2(h0ring + (t & 1) * RING_PAR + j * 32, (unsigned)t, v0, v1);
      f32x4 hv; hv.x = v0.x; hv.y = v0.y; hv.z = v0.z; hv.w = v1.x;
      *reinterpret_cast<f32x4*>(&lh0[lds_idx4(j)]) = hv;
    }
    __syncthreads();  // E
  }

  // ================= tail =================
  // deferred out[SLEN-2] if step SLEN-1 used x
  if (blk == 0 && wv == 4 && (tf1 && mask[SLEN - 1] != 0)) {
    float s = (lyp[lane * 4] + lyp[lane * 4 + 1]) +
              (lyp[lane * 4 + 2] + lyp[lane * 4 + 3]);
    s = dpp_red(s);
    if (lane == 63) out[SLEN - 2] = s + bf;
  }
  // h1[SLEN-1]
  if (L1w) {
    float a[4];
    const f32x4* h0v = reinterpret_cast<const f32x4*>(&lh0[lane * 20]);
    f32x4 p0 = h0v[0], p1 = h0v[1], p2 = h0v[2], p3 = h0v[3];
#pragma unroll
    for (int g = 0; g < 4; ++g)
      a[g] = wA[g] + dot4(W[g][0], p0) + dot4(W[g][1], p1) +
                      dot4(W[g][2], p2) + dot4(W[g][3], p3);
    {
      const f32x4* h1v = reinterpret_cast<const f32x4*>(&lh1[lane * 20]);
      f32x4 q0 = h1v[0], q1 = h1v[1], q2 = h1v[2], q3 = h1v[3];
#pragma unroll
      for (int g = 0; g < 4; ++g) {
        const f32x4* wb = reinterpret_cast<const f32x4*>(
            &wh1_lds[(u * 4 + g) * 1280 + lane * 20]);
        a[g] += dot4(wb[0], q0) + dot4(wb[1], q1) +
                dot4(wb[2], q2) + dot4(wb[3], q3);
      }
    }
#pragma unroll
    for (int g = 0; g < 4; ++g) a[g] = dpp_red(a[g]);
    if (lane == 63) {
      float h = lstm_h(a[0], a[1], a[2], a[3], cc);
      g1h[u] = h; g1yp[u] = wffn * h;
    }
  }
  __syncthreads();
  if (tid < 2) {
    f32x4 v;
    if (tid == 0) { v.x = g1h[0]; v.y = g1h[1]; v.z = g1h[2]; }
    else { v.x = g1h[3]; v.y = (g1yp[0] + g1yp[1]) + (g1yp[2] + g1yp[3]); v.z = 0.f; }
    v.w = __uint_as_float((unsigned)(SLEN - 1));
    st_chunk(h1ring + ((SLEN - 1) & 1) * RING_PAR + blk * 32 + tid * 16, v);
    asm volatile("s_waitcnt vmcnt(0)" ::: "memory");
  }
  if (blk == 0) {
    if (tid < 256) {
      f32x4 v = poll1(h1ring + ((SLEN - 1) & 1) * RING_PAR + tid * 32 + 16,
                      (unsigned)(SLEN - 1));
      lyp[tid] = v.y;
    }
    __syncthreads();
    if (wv == 0) {
      float s = (lyp[lane * 4] + lyp[lane * 4 + 1]) +
                (lyp[lane * 4 + 2] + lyp[lane * 4 + 3]);
      s = dpp_red(s);
      if (lane == 63) out[SLEN - 1] = s + bf;
    }
  }
}

extern "C" void kernel_launch(void* const* d_in, const int* in_sizes, int n_in,
                              void* d_out, int out_size, void* d_ws, size_t ws_size,
                              hipStream_t stream) {
  (void)in_sizes; (void)n_in; (void)out_size; (void)ws_size;
  const float* x      = (const float*)d_in[0];
  const int*   mask   = (const int*)  d_in[1];
  const float* feat   = (const float*)d_in[2];
  const int*   tfp    = (const int*)  d_in[3];
  const float* w_ih0  = (const float*)d_in[4];
  const float* w_hh0  = (const float*)d_in[5];
  const float* b_ih0  = (const float*)d_in[6];
  const float* b_hh0  = (const float*)d_in[7];
  const float* w_ih1  = (const float*)d_in[8];
  const float* w_hh1  = (const float*)d_in[9];
  const float* b_ih1  = (const float*)d_in[10];
  const float* b_hh1  = (const float*)d_in[11];
  const float* w_ffn  = (const float*)d_in[12];
  const float* b_ffn  = (const float*)d_in[13];
  float* out = (float*)d_out;
  char*  ws  = (char*)d_ws;

  hipMemsetAsync(d_ws, 0xFF, (size_t)WS_BYTES, stream);

  lstm_fused<<<dim3(NBLK), dim3(512), 0, stream>>>(
      x, mask, feat, tfp, w_ih0, w_hh0, b_ih0, b_hh0,
      w_ih1, w_hh1, b_ih1, b_hh1, w_ffn, b_ffn, out, ws);
}